// Round 16
// baseline (26.873 us; speedup 1.0000x reference)
//
#include <hip/hip_runtime.h>

#define NBATCH 4
#define NPTS   4096
#define XPT    4                  // x-points per thread
#define XCHUNK (256 * XPT)        // 1024
#define NXC    (NPTS / XCHUNK)    // 4
#define YCHUNK 256                // y-points per block (128 pairs)
#define NPAIR  (YCHUNK / 2)       // 128
#define NYC    (NPTS / YCHUNK)    // 16
#define NBLK   (8 * NYC * NXC)    // 512
#define NCOL   (8 * NXC)          // 32 columns (zc,xc)
#define BIGF   1e30f

typedef float v2f __attribute__((ext_vector_type(2)));

#define LOAD_AG(p)    __hip_atomic_load((p),  __ATOMIC_RELAXED, __HIP_MEMORY_SCOPE_AGENT)
#define STORE_AG(p,v) __hip_atomic_store((p),(v), __ATOMIC_RELAXED, __HIP_MEMORY_SCOPE_AGENT)

// Single-dispatch chamfer. bid = ((zc*NYC+yc)*NXC)+xc.
// All 512 blocks: R15 packed-fma producer -> agent-store partial row, flag1.
// yc==0 blocks (32): spin 15 sibling flags (parallel), fence, column-reduce
//   with PLAIN float4 loads (pipelined, no atomic serialization), mask dir1,
//   block-sum -> colsum + flag2. Column 0's block: spin 31 flag2s, sum,
//   out[0] = total. Flags self-reset by sole consumer; 0xAA/0 != 1 -> safe.
__global__ __launch_bounds__(256)
void chamfer_fused_kernel(const float* __restrict__ preds,
                          const float* __restrict__ gts,
                          const int* __restrict__ mask,
                          float* __restrict__ partial,   // [8][NYC][NPTS]
                          float* __restrict__ colsum,    // [NCOL]
                          unsigned* __restrict__ flag1,  // [NBLK]
                          unsigned* __restrict__ flag2,  // [NCOL]
                          float* __restrict__ out) {
    const int bid = blockIdx.x;
    const int tid = threadIdx.x;
    const int xc  = bid & (NXC - 1);
    const int yc  = (bid >> 2) & (NYC - 1);
    const int zc  = bid >> 6;          // dir*4 + b
    const int dir = zc >> 2;
    const int b   = zc & 3;

    const float* X = (dir == 0 ? preds : gts) + (size_t)b * NPTS * 3;
    const float* Y = (dir == 0 ? gts : preds) + (size_t)b * NPTS * 3;

    // ---------------- producer (R15 packed loop) ----------------
    __shared__ float4 sp[2 * NPAIR];   // 4 KB
    const int cbase = yc * YCHUNK;
    if (tid < NPAIR) {
        const int ja = cbase + 2 * tid;
        const int jb = ja + 1;
        const float xa = Y[ja * 3 + 0], ya = Y[ja * 3 + 1], za = Y[ja * 3 + 2];
        const float xb = Y[jb * 3 + 0], yb = Y[jb * 3 + 1], zb = Y[jb * 3 + 2];
        float ra = xa * xa + ya * ya + za * za;
        float rb = xb * xb + yb * yb + zb * zb;
        if (dir == 0) {
            if (mask[b * NPTS + ja] == 0) ra = BIGF;
            if (mask[b * NPTS + jb] == 0) rb = BIGF;
        }
        sp[2 * tid + 0] = make_float4(xa, xb, ya, yb);
        sp[2 * tid + 1] = make_float4(za, zb, ra, rb);
    }

    v2f A0[XPT], A1[XPT], A2[XPT];
    float rx[XPT], m[XPT];
    const int xbase = xc * XCHUNK + tid;
    #pragma unroll
    for (int i = 0; i < XPT; ++i) {
        const int x = xbase + i * 256;
        const float v0 = X[x * 3 + 0], v1 = X[x * 3 + 1], v2 = X[x * 3 + 2];
        rx[i] = v0 * v0 + v1 * v1 + v2 * v2;
        const float s0 = -2.0f * v0, s1 = -2.0f * v1, s2 = -2.0f * v2;
        A0[i] = (v2f){s0, s0}; A1[i] = (v2f){s1, s1}; A2[i] = (v2f){s2, s2};
        m[i] = BIGF;
    }
    __syncthreads();

    #pragma unroll 2
    for (int j = 0; j < NPAIR; ++j) {
        const float4 E0 = sp[2 * j + 0];
        const float4 E1 = sp[2 * j + 1];
        const v2f X2 = (v2f){E0.x, E0.y};
        const v2f Y2 = (v2f){E0.z, E0.w};
        const v2f Z2 = (v2f){E1.x, E1.y};
        const v2f R2 = (v2f){E1.z, E1.w};
        #pragma unroll
        for (int i = 0; i < XPT; ++i) {
            v2f t = __builtin_elementwise_fma(A2[i], Z2, R2);
            t = __builtin_elementwise_fma(A1[i], Y2, t);
            t = __builtin_elementwise_fma(A0[i], X2, t);
            m[i] = fminf(fminf(m[i], t.x), t.y);   // -> v_min3_f32
        }
    }

    {   // agent-scope stores -> L3 (device-visible; R13-proven fast)
        float* prow = partial + ((size_t)zc * NYC + yc) * NPTS + xbase;
        #pragma unroll
        for (int i = 0; i < XPT; ++i)
            STORE_AG(prow + i * 256, rx[i] + m[i]);
    }
    __syncthreads();

    if (yc != 0) {   // pure producer: release flag, retire
        if (tid == 0)
            __hip_atomic_store(&flag1[bid], 1u, __ATOMIC_RELEASE,
                               __HIP_MEMORY_SCOPE_AGENT);
        return;
    }

    // ---------------- column reducer (32 blocks, yc==0) ----------------
    if (tid < NYC - 1) {   // sibling (zc, yc=tid+1, xc) has bid+4*(tid+1)
        while (LOAD_AG(&flag1[bid + NXC * (tid + 1)]) != 1u)
            __builtin_amdgcn_s_sleep(4);
    }
    __syncthreads();
    __threadfence();   // acquire: invalidate stale cache before plain loads

    // thread t owns float4 x-slot [xc*XCHUNK + 4t .. +3], all 16 rows
    const float4* colbase =
        (const float4*)(partial + (size_t)zc * NYC * NPTS + xc * XCHUNK) + tid;
    float4 m4 = colbase[0];
    #pragma unroll
    for (int r = 1; r < NYC; ++r) {
        const float4 v = colbase[(size_t)r * (NPTS / 4)];
        m4.x = fminf(m4.x, v.x); m4.y = fminf(m4.y, v.y);
        m4.z = fminf(m4.z, v.z); m4.w = fminf(m4.w, v.w);
    }

    float acc;
    const int x0 = xc * XCHUNK + 4 * tid;
    if (dir == 1) {
        const int4 mk = *(const int4*)(mask + b * NPTS + x0);
        acc = (mk.x ? m4.x : 0.0f) + (mk.y ? m4.y : 0.0f)
            + (mk.z ? m4.z : 0.0f) + (mk.w ? m4.w : 0.0f);
    } else {
        acc = m4.x + m4.y + m4.z + m4.w;
    }
    #pragma unroll
    for (int off = 32; off > 0; off >>= 1)
        acc += __shfl_down(acc, off, 64);

    __shared__ float wsum[4];
    __shared__ float s_total;
    if ((tid & 63) == 0) wsum[tid >> 6] = acc;
    __syncthreads();
    if (tid == 0) s_total = wsum[0] + wsum[1] + wsum[2] + wsum[3];
    __syncthreads();

    const int col = zc * NXC + xc;   // 0..31
    if (col != 0) {
        if (tid == 0) {
            STORE_AG(&colsum[col], s_total);
            __hip_atomic_store(&flag2[col], 1u, __ATOMIC_RELEASE,
                               __HIP_MEMORY_SCOPE_AGENT);
        }
        // sole consumer of this column's flag1s: reset for next call
        if (tid < NYC - 1)
            STORE_AG(&flag1[bid + NXC * (tid + 1)], 0u);
        return;
    }

    // ---------------- finalizer (column-0 block) ----------------
    if (tid >= 1 && tid < NCOL) {
        while (LOAD_AG(&flag2[tid]) != 1u)
            __builtin_amdgcn_s_sleep(4);
    }
    __syncthreads();
    __threadfence();

    float v = 0.0f;
    if (tid >= 1 && tid < NCOL) v = LOAD_AG(&colsum[tid]);
    if (tid == 0) v = s_total;
    #pragma unroll
    for (int off = 16; off > 0; off >>= 1)
        v += __shfl_down(v, off, 32);
    if (tid == 0) out[0] = v;

    if (tid >= 1 && tid < NCOL) STORE_AG(&flag2[tid], 0u);
    if (tid < NYC - 1)
        STORE_AG(&flag1[bid + NXC * (tid + 1)], 0u);
}

extern "C" void kernel_launch(void* const* d_in, const int* in_sizes, int n_in,
                              void* d_out, int out_size, void* d_ws, size_t ws_size,
                              hipStream_t stream) {
    const float* preds = (const float*)d_in[0];  // [B, Npred, 3]
    const float* gts   = (const float*)d_in[1];  // [B, Ngt, 3]
    const int*   mask  = (const int*)d_in[2];    // [B, Ngt]
    float* out = (float*)d_out;

    float*    partial = (float*)d_ws;                         // 2 MB
    float*    colsum  = partial + (size_t)8 * NYC * NPTS;     // [32]
    unsigned* flag1   = (unsigned*)(colsum + NCOL);           // [512]
    unsigned* flag2   = flag1 + NBLK;                         // [32]

    chamfer_fused_kernel<<<NBLK, 256, 0, stream>>>(
        preds, gts, mask, partial, colsum, flag1, flag2, out);
}

// Round 17
// 19.219 us; speedup vs baseline: 1.3982x; 1.3982x over previous
//
#include <hip/hip_runtime.h>

#define NBATCH 4
#define NPTS   4096
#define XPT    2                  // x-points per thread
#define XCHUNK (256 * XPT)        // 512
#define NXC    (NPTS / XCHUNK)    // 8
#define YCHUNK 256                // y-points per block (128 pairs)
#define NPAIR  (YCHUNK / 2)       // 128
#define NYC    (NPTS / YCHUNK)    // 16
#define BIGF   1e30f

typedef float v2f __attribute__((ext_vector_type(2)));

// Kernel 1: partial mins with packed-f32 math.
// grid = (NXC, NYC, 2*NBATCH) = (8,16,8) = 1024 blocks (4/CU, 4 waves/SIMD).
// LDS pair layout per y-pair j: E0=(x_a,x_b,y_a,y_b), E1=(z_a,z_b,ry_a,ry_b)
// -> inner step per x: 3 v_pk_fma_f32 + 1 v_min3_f32 for TWO y (2 instr/pair).
__global__ __launch_bounds__(256)
void chamfer_min_kernel(const float* __restrict__ preds,
                        const float* __restrict__ gts,
                        const int* __restrict__ mask,
                        float* __restrict__ partial,
                        float* __restrict__ out) {
    const int zc  = blockIdx.z;
    const int dir = zc >> 2;
    const int b   = zc & 3;
    const int tid = threadIdx.x;

    // zero the output scalar exactly once (kernel2 accumulates after boundary)
    if ((zc | blockIdx.x | blockIdx.y | tid) == 0) out[0] = 0.0f;

    const float* X = (dir == 0 ? preds : gts) + (size_t)b * NPTS * 3;
    const float* Y = (dir == 0 ? gts : preds) + (size_t)b * NPTS * 3;

    __shared__ float4 sp[2 * NPAIR];   // 4 KB
    const int cbase = blockIdx.y * YCHUNK;
    if (tid < NPAIR) {
        const int ja = cbase + 2 * tid;
        const int jb = ja + 1;
        const float xa = Y[ja * 3 + 0], ya = Y[ja * 3 + 1], za = Y[ja * 3 + 2];
        const float xb = Y[jb * 3 + 0], yb = Y[jb * 3 + 1], zb = Y[jb * 3 + 2];
        float ra = xa * xa + ya * ya + za * za;
        float rb = xb * xb + yb * yb + zb * zb;
        if (dir == 0) {
            if (mask[b * NPTS + ja] == 0) ra = BIGF;
            if (mask[b * NPTS + jb] == 0) rb = BIGF;
        }
        sp[2 * tid + 0] = make_float4(xa, xb, ya, yb);
        sp[2 * tid + 1] = make_float4(za, zb, ra, rb);
    }

    // load XPT x-points; hoist packed splats of (-2x) out of the y-loop
    v2f A0[XPT], A1[XPT], A2[XPT];
    float rx[XPT], m[XPT];
    const int xbase = blockIdx.x * XCHUNK + tid;
    #pragma unroll
    for (int i = 0; i < XPT; ++i) {
        const int x = xbase + i * 256;
        const float v0 = X[x * 3 + 0], v1 = X[x * 3 + 1], v2 = X[x * 3 + 2];
        rx[i] = v0 * v0 + v1 * v1 + v2 * v2;
        const float s0 = -2.0f * v0, s1 = -2.0f * v1, s2 = -2.0f * v2;
        A0[i] = (v2f){s0, s0}; A1[i] = (v2f){s1, s1}; A2[i] = (v2f){s2, s2};
        m[i] = BIGF;
    }
    __syncthreads();

    #pragma unroll 4
    for (int j = 0; j < NPAIR; ++j) {
        const float4 E0 = sp[2 * j + 0];   // (x_a,x_b,y_a,y_b) broadcast
        const float4 E1 = sp[2 * j + 1];   // (z_a,z_b,ra,rb)
        const v2f X2 = (v2f){E0.x, E0.y};
        const v2f Y2 = (v2f){E0.z, E0.w};
        const v2f Z2 = (v2f){E1.x, E1.y};
        const v2f R2 = (v2f){E1.z, E1.w};
        #pragma unroll
        for (int i = 0; i < XPT; ++i) {
            // t = R2 + A2*Z2 + A1*Y2 + A0*X2  (3 x v_pk_fma_f32)
            v2f t = __builtin_elementwise_fma(A2[i], Z2, R2);
            t = __builtin_elementwise_fma(A1[i], Y2, t);
            t = __builtin_elementwise_fma(A0[i], X2, t);
            m[i] = fminf(fminf(m[i], t.x), t.y);   // -> v_min3_f32
        }
    }

    float* prow = partial + ((size_t)zc * NYC + blockIdx.y) * NPTS + xbase;
    #pragma unroll
    for (int i = 0; i < XPT; ++i)
        prow[i * 256] = rx[i] + m[i];
}

// Kernel 2: per point min over NYC=16 rows. 2 threads per float4-column
// (8 rows each, shfl_xor combine) -> 64 blocks of 256.
__global__ __launch_bounds__(256)
void chamfer_reduce_kernel(const float* __restrict__ partial,
                           const int* __restrict__ mask,
                           float* __restrict__ out) {
    const int gid = blockIdx.x * blockDim.x + threadIdx.x;
    const int h   = gid & 1;            // row-half
    const int c   = gid >> 1;           // float4-column id
    const int p4  = c * 4;              // first of 4 consecutive points
    const int dir = p4 >> 14;
    const int b   = (p4 >> 12) & 3;
    const int x   = p4 & 4095;
    const int zc  = dir * NBATCH + b;

    const float4* base = (const float4*)(partial + (size_t)zc * NYC * NPTS + x)
                       + (size_t)(h * 8) * (NPTS / 4);
    float4 m4 = base[0];
    #pragma unroll
    for (int r = 1; r < 8; ++r) {
        const float4 v = base[(size_t)r * (NPTS / 4)];
        m4.x = fminf(m4.x, v.x); m4.y = fminf(m4.y, v.y);
        m4.z = fminf(m4.z, v.z); m4.w = fminf(m4.w, v.w);
    }
    // combine halves (lanes 2i, 2i+1)
    m4.x = fminf(m4.x, __shfl_xor(m4.x, 1, 64));
    m4.y = fminf(m4.y, __shfl_xor(m4.y, 1, 64));
    m4.z = fminf(m4.z, __shfl_xor(m4.z, 1, 64));
    m4.w = fminf(m4.w, __shfl_xor(m4.w, 1, 64));

    float acc = 0.0f;
    if (h == 0) {
        if (dir == 1) {
            const int4 mk = *(const int4*)(mask + b * NPTS + x);
            acc = (mk.x ? m4.x : 0.0f) + (mk.y ? m4.y : 0.0f)
                + (mk.z ? m4.z : 0.0f) + (mk.w ? m4.w : 0.0f);
        } else {
            acc = m4.x + m4.y + m4.z + m4.w;
        }
    }

    #pragma unroll
    for (int off = 32; off > 0; off >>= 1)
        acc += __shfl_down(acc, off, 64);

    __shared__ float wsum[4];
    if ((threadIdx.x & 63) == 0) wsum[threadIdx.x >> 6] = acc;
    __syncthreads();
    if (threadIdx.x == 0)
        atomicAdd(out, wsum[0] + wsum[1] + wsum[2] + wsum[3]);
}

extern "C" void kernel_launch(void* const* d_in, const int* in_sizes, int n_in,
                              void* d_out, int out_size, void* d_ws, size_t ws_size,
                              hipStream_t stream) {
    const float* preds = (const float*)d_in[0];  // [B, Npred, 3]
    const float* gts   = (const float*)d_in[1];  // [B, Ngt, 3]
    const int*   mask  = (const int*)d_in[2];    // [B, Ngt]
    float* out = (float*)d_out;

    float* partial = (float*)d_ws;  // [8][NYC][NPTS] = 2 MB

    dim3 grid(NXC, NYC, 2 * NBATCH);
    chamfer_min_kernel<<<grid, 256, 0, stream>>>(preds, gts, mask, partial, out);

    chamfer_reduce_kernel<<<2 * (2 * NBATCH * NPTS / 4) / 256, 256, 0, stream>>>(
        partial, mask, out);
}